// Round 13
// baseline (157.194 us; speedup 1.0000x reference)
//
#include <hip/hip_runtime.h>
#include <hip/hip_bf16.h>
#include <stdint.h>

typedef __attribute__((ext_vector_type(8))) short short8;
typedef __attribute__((ext_vector_type(4))) float f32x4;
typedef __attribute__((ext_vector_type(16))) float f32x16;

#define QSCALE 0.18033688011112042f   // (1/8) * log2(e): folds softmax /sqrt(64) AND exp->exp2

__device__ __forceinline__ unsigned short f2bf(float f) {
  unsigned int u = __builtin_bit_cast(unsigned int, f);
  u += 0x7FFFu + ((u >> 16) & 1u);   // RNE
  return (unsigned short)(u >> 16);
}

__device__ __forceinline__ unsigned short f2bf_fast(float f) {
  __hip_bfloat16 h = __float2bfloat16(f);
  return __builtin_bit_cast(unsigned short, h);
}

__device__ __forceinline__ float exp2_fast(float x) {
  float r; asm("v_exp_f32 %0, %1" : "=v"(r) : "v"(x)); return r;   // 2^x
}

#define GLD_LDS16(gp, lp) \
  __builtin_amdgcn_global_load_lds((const __attribute__((address_space(1))) void*)(gp), \
                                   (__attribute__((address_space(3))) void*)(lp), 16, 0, 0)

// ---------------- fused fp32 -> bf16 convert for x / Wqkv (q-rows pre-scaled) / Wo ------
__global__ __launch_bounds__(256) void cvt_all_kernel(
    const float* __restrict__ x, const float* __restrict__ Wqkv, const float* __restrict__ Wo,
    unsigned short* __restrict__ xb, unsigned short* __restrict__ Wqkvb,
    unsigned short* __restrict__ Wob) {
  int i = blockIdx.x * 256 + threadIdx.x;          // indexes 8-float chunks
  const float* src; unsigned short* dst; int local; float scale = 1.0f;
  if (i < 1048576) { src = x; dst = xb; local = i; }
  else if (i < 1048576 + 393216) {
    local = i - 1048576; src = Wqkv; dst = Wqkvb;
    int row = (local * 8) >> 10;                   // K = 1024 per row
    if (((row >> 6) % 3) == 0) scale = QSCALE;     // q rows: fold 1/sqrt(64) * log2(e)
  } else { local = i - 1441792; src = Wo; dst = Wob; }
  const float4* s4 = (const float4*)src;
  float4 a = s4[local * 2], b = s4[local * 2 + 1];
  uint4 o;
  o.x = (unsigned)f2bf(a.x * scale) | ((unsigned)f2bf(a.y * scale) << 16);
  o.y = (unsigned)f2bf(a.z * scale) | ((unsigned)f2bf(a.w * scale) << 16);
  o.z = (unsigned)f2bf(b.x * scale) | ((unsigned)f2bf(b.y * scale) << 16);
  o.w = (unsigned)f2bf(b.z * scale) | ((unsigned)f2bf(b.w * scale) << 16);
  *(uint4*)(dst + (size_t)local * 8) = o;
}

// ---------------- 128x128-tile bf16 GEMM, C = A @ B^T (+bias), m97 structure ----------
// EPI 0: scatter q/k as [B][H][S][64], v TRANSPOSED as [B][H][64][S]   EPI 1: fp32 [M][N]
template<int EPI>
__global__ __launch_bounds__(256, 4) void gemm_bt(
    const unsigned short* __restrict__ A, const unsigned short* __restrict__ Bw,
    const float* __restrict__ bias, void* o0, void* o1, void* o2,
    int M, int N, int K, int nbc)
{
  __shared__ __align__(16) unsigned short Asm[128 * 64];
  __shared__ __align__(16) unsigned short Bsm[128 * 64];
  int bid = blockIdx.x;
  int bc = bid % nbc, br = bid / nbc;
  int tid = threadIdx.x;
  int lane = tid & 63, w = tid >> 6;
  int l16 = lane & 15, g = lane >> 4;
  int wr = w >> 1, wc = w & 1;
  f32x4 acc[4][4];
  #pragma unroll
  for (int i = 0; i < 4; i++)
    #pragma unroll
    for (int j = 0; j < 4; j++) acc[i][j] = (f32x4){0.f, 0.f, 0.f, 0.f};

  const int nkt = K >> 6;
  for (int kt = 0; kt < nkt; ++kt) {
    __syncthreads();
    #pragma unroll
    for (int r = 0; r < 4; ++r) {
      int idx = tid + 256 * r;            // lane-contiguous per wave (gload_lds linear dest)
      int row = idx >> 3, s = idx & 7;
      int gofs = ((s ^ (row & 7)) << 3) + (kt << 6);   // pre-swizzled global source
      GLD_LDS16(A + (size_t)(br * 128 + row) * K + gofs, &Asm[idx << 3]);
      GLD_LDS16(Bw + (size_t)(bc * 128 + row) * K + gofs, &Bsm[idx << 3]);
    }
    __syncthreads();
    #pragma unroll
    for (int kk = 0; kk < 2; ++kk) {
      short8 af[4], bf[4];
      #pragma unroll
      for (int i = 0; i < 4; i++) {
        int rowa = wr * 64 + i * 16 + l16;
        af[i] = *(const short8*)&Asm[(rowa << 6) + ((((kk << 2) + g) ^ (rowa & 7)) << 3)];
        int rowb = wc * 64 + i * 16 + l16;
        bf[i] = *(const short8*)&Bsm[(rowb << 6) + ((((kk << 2) + g) ^ (rowb & 7)) << 3)];
      }
      #pragma unroll
      for (int i = 0; i < 4; i++)
        #pragma unroll
        for (int j = 0; j < 4; j++)
          acc[i][j] = __builtin_amdgcn_mfma_f32_16x16x32_bf16(af[i], bf[j], acc[i][j], 0, 0, 0);
    }
  }
  // epilogue: D row = g*4+jj, col = l16 (m89-verified layout)
  #pragma unroll
  for (int i = 0; i < 4; i++) {
    #pragma unroll
    for (int j = 0; j < 4; j++) {
      int n = bc * 128 + wc * 64 + j * 16 + l16;
      int m0 = br * 128 + wr * 64 + i * 16 + g * 4;
      if (EPI == 0) {
        int t = (n >> 6) % 3;
        int hh = n / 192, e = n & 63;
        float bval = bias[n]; if (t == 0) bval *= QSCALE;
        int bb = m0 >> 12, s0 = m0 & 4095;          // S = 4096; m0 4-aligned, no b-straddle
        if (t == 2) {                               // v: transposed [bh][e][S], b64-packed
          unsigned short p0 = f2bf(acc[i][j][0] + bval);
          unsigned short p1 = f2bf(acc[i][j][1] + bval);
          unsigned short p2 = f2bf(acc[i][j][2] + bval);
          unsigned short p3 = f2bf(acc[i][j][3] + bval);
          uint2 pk;
          pk.x = (unsigned)p0 | ((unsigned)p1 << 16);
          pk.y = (unsigned)p2 | ((unsigned)p3 << 16);
          unsigned short* vt = (unsigned short*)o2;
          *(uint2*)&vt[(((size_t)(bb * 16 + hh) * 64 + e) << 12) + s0] = pk;
        } else {
          unsigned short* dst = (unsigned short*)(t == 0 ? o0 : o1);
          #pragma unroll
          for (int jj = 0; jj < 4; jj++)
            dst[((((size_t)(bb * 16 + hh) << 12) + s0 + jj) << 6) + e] = f2bf(acc[i][j][jj] + bval);
        }
      } else {
        float* o = (float*)o0;
        float bval = bias[n];
        #pragma unroll
        for (int jj = 0; jj < 4; jj++)
          o[(size_t)(m0 + jj) * N + n] = acc[i][j][jj] + bval;
      }
    }
  }
}

// ---------------- banded flash attention (QBLK=128, 32x32x16 MFMA, 32 q-rows/wave) -----
// grid: 1024 blocks; 4 waves/block, wave owns 32 query rows. 32x32 fragments read 2x
// rows per LDS byte vs 16x16 (r12 was LDS-throughput-bound: 18 b128/tile/16rows -> 20
// b128/tile/32rows). All LDS reads use the proven slot^(row&7) swizzle (conflicts=0).
// C/D layout (m101): col=lane&31, row=(reg&3)+8*(reg>>2)+4*(lane>>5).
__global__ __launch_bounds__(256, 3) void attn_kernel(
    const unsigned short* __restrict__ qb, const unsigned short* __restrict__ kb,
    const unsigned short* __restrict__ vtb, const int* __restrict__ pmask,
    unsigned short* __restrict__ ctxb)
{
  const int S = 4096, WIN = 256;
  const float NEG = -1e38f;
  __shared__ __align__(16) unsigned short Ks[2][64 * 64];    // 16 KB
  __shared__ __align__(16) unsigned short Vts[2][64 * 64];   // 16 KB
  __shared__ __align__(16) unsigned short Ps[4][32 * 64];    // 16 KB (per wave)

  int bid0 = blockIdx.x;
  int bid = (bid0 & 7) * (gridDim.x >> 3) + (bid0 >> 3);   // XCD swizzle: 4 heads per XCD L2
  int qt = bid & 31;            // S/128 tiles
  int bh = bid >> 5;
  int b = bh >> 4, h = bh & 15;

  const unsigned short* Q  = qb + (size_t)bh * S * 64;
  const unsigned short* Kg = kb + (size_t)bh * S * 64;
  const unsigned short* Vt = vtb + (size_t)bh * 64 * S;
  const int* pmrow = pmask + (size_t)b * S;

  int tid = threadIdx.x;
  int lane = tid & 63, w = tid >> 6;    // 4 waves
  int l32 = lane & 31, h2 = lane >> 5;  // half-wave index

  int q0 = qt * 128;
  int Q0 = q0 + w * 32;                 // this wave's 32 query rows

  // Q fragments: A[m=l32][k = c*16 + h2*8 .. +8]
  short8 qf[4];
  #pragma unroll
  for (int c = 0; c < 4; ++c)
    qf[c] = *(const short8*)&Q[(size_t)(Q0 + l32) * 64 + c * 16 + h2 * 8];

  f32x16 ctx0 = (f32x16)(0.f), ctx1 = (f32x16)(0.f);
  float lrun[16];
  #pragma unroll
  for (int r = 0; r < 16; ++r) lrun[r] = 0.f;

  int kt0 = (q0 - WIN) >> 6; if (kt0 < 0) kt0 = 0;
  int kt1 = (q0 + 127 + WIN) >> 6; if (kt1 > 63) kt1 = 63;
  int nt = kt1 - kt0 + 1;

  // 256 threads stage one 64x64 K-unit and one 64x64 Vt-unit (8 KB each, 2 gloads ea.)
#define STAGE(BUF, KT) do {                                                       \
    int kb_ = (KT) * 64;                                                          \
    _Pragma("unroll")                                                             \
    for (int r_ = 0; r_ < 2; ++r_) {                                              \
      int idx_ = tid + 256 * r_;                                                  \
      int row_ = idx_ >> 3, s_ = idx_ & 7;                                        \
      int c_ = (s_ ^ (row_ & 7)) << 3;                                            \
      GLD_LDS16(Kg + (size_t)(kb_ + row_) * 64 + c_, &Ks[BUF][idx_ << 3]);        \
      GLD_LDS16(Vt + (size_t)row_ * S + kb_ + c_, &Vts[BUF][idx_ << 3]);          \
    }                                                                             \
  } while (0)

  STAGE(0, kt0);
  asm volatile("s_waitcnt vmcnt(0)" ::: "memory");
  __syncthreads();

  int cur = 0;
  for (int it = 0; it < nt; ++it) {
    int kbase = (kt0 + it) * 64;
    if (it + 1 < nt) STAGE(cur ^ 1, kt0 + it + 1);

    bool need = (kbase >= Q0 - 319) && (kbase <= Q0 + 287);
    if (need) {
      unsigned long long bm = __ballot(pmrow[kbase + lane] != 0);
      bool allv = (~bm == 0ULL);
      bool full = (kbase >= Q0 - 225) && (kbase <= Q0 + 193);   // all 32 rows in band

      // QK^T: sc[kg] = D[q 32][keys 32], keys = kg*32 + l32
      f32x16 sc0 = (f32x16)(0.f), sc1 = (f32x16)(0.f);
      int krow0 = l32, krow1 = 32 + l32;
      __builtin_amdgcn_s_setprio(1);
      #pragma unroll
      for (int c = 0; c < 4; ++c) {
        int slot = c * 2 + h2;
        short8 kf0 = *(const short8*)&Ks[cur][(krow0 << 6) + ((slot ^ (krow0 & 7)) << 3)];
        sc0 = __builtin_amdgcn_mfma_f32_32x32x16_bf16(qf[c], kf0, sc0, 0, 0, 0);
        short8 kf1 = *(const short8*)&Ks[cur][(krow1 << 6) + ((slot ^ (krow1 & 7)) << 3)];
        sc1 = __builtin_amdgcn_mfma_f32_32x32x16_bf16(qf[c], kf1, sc1, 0, 0, 0);
      }
      __builtin_amdgcn_s_setprio(0);

      int col0 = l32, col1 = 32 + l32;
      if (!full) {                      // band-edge tiles: mask out-of-band
        #pragma unroll
        for (int r = 0; r < 16; ++r) {
          int row = (r & 3) + 8 * (r >> 2) + 4 * h2;
          int d0 = kbase + col0 - (Q0 + row) + WIN;
          sc0[r] = ((unsigned)d0 <= 2u * WIN) ? sc0[r] : NEG;
          int d1 = kbase + col1 - (Q0 + row) + WIN;
          sc1[r] = ((unsigned)d1 <= 2u * WIN) ? sc1[r] : NEG;
        }
      }
      // exp2 + P store (swizzled [32][64]); padding via ballot bits
      unsigned bit0 = (unsigned)(bm >> col0) & 1u;
      unsigned bit1 = (unsigned)(bm >> col1) & 1u;
      #pragma unroll
      for (int r = 0; r < 16; ++r) {
        int row = (r & 3) + 8 * (r >> 2) + 4 * h2;
        float p0 = exp2_fast(sc0[r]);
        float p1 = exp2_fast(sc1[r]);
        if (!allv) { p0 = bit0 ? p0 : 0.f; p1 = bit1 ? p1 : 0.f; }
        lrun[r] += p0 + p1;
        int rb = (row << 6), rx = (row & 7);
        Ps[w][rb + ((((col0 >> 3) ^ rx) << 3) | (col0 & 7))] = f2bf_fast(p0);
        Ps[w][rb + ((((col1 >> 3) ^ rx) << 3) | (col1 & 7))] = f2bf_fast(p1);
      }

      asm volatile("s_waitcnt lgkmcnt(0)" ::: "memory");  // P visible wave-wide
      __builtin_amdgcn_sched_barrier(0);

      // PV: ctx[q 32][d 64]: A = P[m=l32][k-chunk], B = V[k][d = dg*32 + l32]
      __builtin_amdgcn_s_setprio(1);
      #pragma unroll
      for (int c = 0; c < 4; ++c) {
        int slot = c * 2 + h2;
        short8 pf = *(const short8*)&Ps[w][(l32 << 6) + ((slot ^ (l32 & 7)) << 3)];
        int dr0 = l32, dr1 = 32 + l32;
        short8 vf0 = *(const short8*)&Vts[cur][(dr0 << 6) + ((slot ^ (dr0 & 7)) << 3)];
        ctx0 = __builtin_amdgcn_mfma_f32_32x32x16_bf16(pf, vf0, ctx0, 0, 0, 0);
        short8 vf1 = *(const short8*)&Vts[cur][(dr1 << 6) + ((slot ^ (dr1 & 7)) << 3)];
        ctx1 = __builtin_amdgcn_mfma_f32_32x32x16_bf16(pf, vf1, ctx1, 0, 0, 0);
      }
      __builtin_amdgcn_s_setprio(0);
    }

    if (it + 1 < nt) {
      asm volatile("s_waitcnt vmcnt(0)" ::: "memory");  // next tile landed
      __syncthreads();
      cur ^= 1;
    }
  }
#undef STAGE

  // denominator: reduce lrun[r] across the 32-lane half (row depends only on r, h2)
  #pragma unroll
  for (int r = 0; r < 16; ++r) {
    float ps = lrun[r];
    #pragma unroll
    for (int mk = 1; mk < 32; mk <<= 1) ps += __shfl_xor(ps, mk);
    lrun[r] = (ps > 0.f) ? (1.f / ps) : 0.f;
  }
  // write ctx as bf16 in [B][S][H*64]
  #pragma unroll
  for (int r = 0; r < 16; ++r) {
    int row = (r & 3) + 8 * (r >> 2) + 4 * h2;
    int qrow = Q0 + row;
    size_t base = ((size_t)b * S + qrow) * 1024 + h * 64;
    ctxb[base + l32]      = f2bf(ctx0[r] * lrun[r]);
    ctxb[base + 32 + l32] = f2bf(ctx1[r] * lrun[r]);
  }
}

// ---------------- launch ----------------------------------------------------------------
extern "C" void kernel_launch(void* const* d_in, const int* in_sizes, int n_in,
                              void* d_out, int out_size, void* d_ws, size_t ws_size,
                              hipStream_t stream) {
  const float* x     = (const float*)d_in[0];
  const int*   pmask = (const int*)d_in[1];
  const float* Wqkv  = (const float*)d_in[2];
  const float* bqkv  = (const float*)d_in[3];
  const float* Wo    = (const float*)d_in[4];
  const float* bo    = (const float*)d_in[5];

  // Memory map (56MB of ws + d_out doubling as q/k scratch):
  //   ws:    xb@0 (16MB) | Wqkvb@16MB (6MB) | Wob@22MB (2MB) | vtb@24MB (16MB) | ctxb@40MB (16MB)
  //   d_out: qbuf@0 (16MB) | kbuf@16MB (16MB)  -- dead before final GEMM overwrites d_out
  char* wsp = (char*)d_ws;
  unsigned short* xb    = (unsigned short*)(wsp);
  unsigned short* Wqkvb = (unsigned short*)(wsp + (size_t)(16u << 20));
  unsigned short* Wob   = (unsigned short*)(wsp + (size_t)(22u << 20));
  unsigned short* vtb   = (unsigned short*)(wsp + (size_t)(24u << 20));
  unsigned short* ctxb  = (unsigned short*)(wsp + (size_t)(40u << 20));
  unsigned short* qbuf  = (unsigned short*)d_out;
  unsigned short* kbuf  = (unsigned short*)d_out + (size_t)8388608;  // +16MB

  cvt_all_kernel<<<6144, 256, 0, stream>>>(x, Wqkv, Wo, xb, Wqkvb, Wob);

  gemm_bt<0><<<(8192 / 128) * (3072 / 128), 256, 0, stream>>>(
      xb, Wqkvb, bqkv, qbuf, kbuf, vtb, 8192, 3072, 1024, 3072 / 128);

  attn_kernel<<<1024, 256, 0, stream>>>(qbuf, kbuf, vtb, pmask, ctxb);

  gemm_bt<1><<<(8192 / 128) * (1024 / 128), 256, 0, stream>>>(
      ctxb, Wob, bo, d_out, nullptr, nullptr, 8192, 1024, 1024, 1024 / 128);
}

// Round 14
// 153.109 us; speedup vs baseline: 1.0267x; 1.0267x over previous
//
#include <hip/hip_runtime.h>
#include <hip/hip_bf16.h>
#include <stdint.h>

typedef __attribute__((ext_vector_type(8))) short short8;
typedef __attribute__((ext_vector_type(4))) float f32x4;

#define QSCALE 0.18033688011112042f   // (1/8) * log2(e): folds softmax /sqrt(64) AND exp->exp2

__device__ __forceinline__ unsigned short f2bf(float f) {
  unsigned int u = __builtin_bit_cast(unsigned int, f);
  u += 0x7FFFu + ((u >> 16) & 1u);   // RNE
  return (unsigned short)(u >> 16);
}

__device__ __forceinline__ unsigned short f2bf_fast(float f) {
  __hip_bfloat16 h = __float2bfloat16(f);
  return __builtin_bit_cast(unsigned short, h);
}

__device__ __forceinline__ float exp2_fast(float x) {
  float r; asm("v_exp_f32 %0, %1" : "=v"(r) : "v"(x)); return r;   // 2^x
}

#define GLD_LDS16(gp, lp) \
  __builtin_amdgcn_global_load_lds((const __attribute__((address_space(1))) void*)(gp), \
                                   (__attribute__((address_space(3))) void*)(lp), 16, 0, 0)

// ---------------- fused fp32 -> bf16 convert for x / Wqkv (q-rows pre-scaled) / Wo ------
__global__ __launch_bounds__(256) void cvt_all_kernel(
    const float* __restrict__ x, const float* __restrict__ Wqkv, const float* __restrict__ Wo,
    unsigned short* __restrict__ xb, unsigned short* __restrict__ Wqkvb,
    unsigned short* __restrict__ Wob) {
  int i = blockIdx.x * 256 + threadIdx.x;          // indexes 8-float chunks
  const float* src; unsigned short* dst; int local; float scale = 1.0f;
  if (i < 1048576) { src = x; dst = xb; local = i; }
  else if (i < 1048576 + 393216) {
    local = i - 1048576; src = Wqkv; dst = Wqkvb;
    int row = (local * 8) >> 10;                   // K = 1024 per row
    if (((row >> 6) % 3) == 0) scale = QSCALE;     // q rows: fold 1/sqrt(64) * log2(e)
  } else { local = i - 1441792; src = Wo; dst = Wob; }
  const float4* s4 = (const float4*)src;
  float4 a = s4[local * 2], b = s4[local * 2 + 1];
  uint4 o;
  o.x = (unsigned)f2bf(a.x * scale) | ((unsigned)f2bf(a.y * scale) << 16);
  o.y = (unsigned)f2bf(a.z * scale) | ((unsigned)f2bf(a.w * scale) << 16);
  o.z = (unsigned)f2bf(b.x * scale) | ((unsigned)f2bf(b.y * scale) << 16);
  o.w = (unsigned)f2bf(b.z * scale) | ((unsigned)f2bf(b.w * scale) << 16);
  *(uint4*)(dst + (size_t)local * 8) = o;
}

// ---------------- 128x128-tile bf16 GEMM, C = A @ B^T (+bias), m97 structure ----------
// EPI 0: scatter q/k as [B][H][S][64], v TRANSPOSED as [B][H][64][S]   EPI 1: fp32 [M][N]
template<int EPI>
__global__ __launch_bounds__(256, 4) void gemm_bt(
    const unsigned short* __restrict__ A, const unsigned short* __restrict__ Bw,
    const float* __restrict__ bias, void* o0, void* o1, void* o2,
    int M, int N, int K, int nbc)
{
  __shared__ __align__(16) unsigned short Asm[128 * 64];
  __shared__ __align__(16) unsigned short Bsm[128 * 64];
  int bid = blockIdx.x;
  int bc = bid % nbc, br = bid / nbc;
  int tid = threadIdx.x;
  int lane = tid & 63, w = tid >> 6;
  int l16 = lane & 15, g = lane >> 4;
  int wr = w >> 1, wc = w & 1;
  f32x4 acc[4][4];
  #pragma unroll
  for (int i = 0; i < 4; i++)
    #pragma unroll
    for (int j = 0; j < 4; j++) acc[i][j] = (f32x4){0.f, 0.f, 0.f, 0.f};

  const int nkt = K >> 6;
  for (int kt = 0; kt < nkt; ++kt) {
    __syncthreads();
    #pragma unroll
    for (int r = 0; r < 4; ++r) {
      int idx = tid + 256 * r;            // lane-contiguous per wave (gload_lds linear dest)
      int row = idx >> 3, s = idx & 7;
      int gofs = ((s ^ (row & 7)) << 3) + (kt << 6);   // pre-swizzled global source
      GLD_LDS16(A + (size_t)(br * 128 + row) * K + gofs, &Asm[idx << 3]);
      GLD_LDS16(Bw + (size_t)(bc * 128 + row) * K + gofs, &Bsm[idx << 3]);
    }
    __syncthreads();
    #pragma unroll
    for (int kk = 0; kk < 2; ++kk) {
      short8 af[4], bf[4];
      #pragma unroll
      for (int i = 0; i < 4; i++) {
        int rowa = wr * 64 + i * 16 + l16;
        af[i] = *(const short8*)&Asm[(rowa << 6) + ((((kk << 2) + g) ^ (rowa & 7)) << 3)];
        int rowb = wc * 64 + i * 16 + l16;
        bf[i] = *(const short8*)&Bsm[(rowb << 6) + ((((kk << 2) + g) ^ (rowb & 7)) << 3)];
      }
      #pragma unroll
      for (int i = 0; i < 4; i++)
        #pragma unroll
        for (int j = 0; j < 4; j++)
          acc[i][j] = __builtin_amdgcn_mfma_f32_16x16x32_bf16(af[i], bf[j], acc[i][j], 0, 0, 0);
    }
  }
  // epilogue: D row = g*4+jj, col = l16 (m89-verified layout)
  #pragma unroll
  for (int i = 0; i < 4; i++) {
    #pragma unroll
    for (int j = 0; j < 4; j++) {
      int n = bc * 128 + wc * 64 + j * 16 + l16;
      int m0 = br * 128 + wr * 64 + i * 16 + g * 4;
      if (EPI == 0) {
        int t = (n >> 6) % 3;
        int hh = n / 192, e = n & 63;
        float bval = bias[n]; if (t == 0) bval *= QSCALE;
        int bb = m0 >> 12, s0 = m0 & 4095;          // S = 4096; m0 4-aligned, no b-straddle
        if (t == 2) {                               // v: transposed [bh][e][S], b64-packed
          unsigned short p0 = f2bf(acc[i][j][0] + bval);
          unsigned short p1 = f2bf(acc[i][j][1] + bval);
          unsigned short p2 = f2bf(acc[i][j][2] + bval);
          unsigned short p3 = f2bf(acc[i][j][3] + bval);
          uint2 pk;
          pk.x = (unsigned)p0 | ((unsigned)p1 << 16);
          pk.y = (unsigned)p2 | ((unsigned)p3 << 16);
          unsigned short* vt = (unsigned short*)o2;
          *(uint2*)&vt[(((size_t)(bb * 16 + hh) * 64 + e) << 12) + s0] = pk;
        } else {
          unsigned short* dst = (unsigned short*)(t == 0 ? o0 : o1);
          #pragma unroll
          for (int jj = 0; jj < 4; jj++)
            dst[((((size_t)(bb * 16 + hh) << 12) + s0 + jj) << 6) + e] = f2bf(acc[i][j][jj] + bval);
        }
      } else {
        float* o = (float*)o0;
        float bval = bias[n];
        #pragma unroll
        for (int jj = 0; jj < 4; jj++)
          o[(size_t)(m0 + jj) * N + n] = acc[i][j][jj] + bval;
      }
    }
  }
}

// ---------------- banded flash attention (QBLK=128, 16x16 MFMA, shared K/V frags) ------
// grid: 1024 blocks; 4 waves/block, wave owns 32 q-rows as 2 q-sets of 16.
// r13's 32x32 regressed: 4-way bank conflict is STRUCTURAL for 32-row fragment reads
// with 128B-row gload_lds staging (bank = chunk^(row&7), 8 classes). Back to 16x16
// (2-way = free, measured 0). New: K/V fragment pairs are q-set-independent -> read
// ONCE per tile, feed both q-sets' MFMA chains (LDS b128/tile/32rows: 36 -> 20).
// Register discipline (r10 lesson): only one kf/vf PAIR live at a time; mask+exp+P-store
// fused per k4 so score regs die immediately. All LDS addr expressions r12-exact.
__global__ __launch_bounds__(256, 4) void attn_kernel(
    const unsigned short* __restrict__ qb, const unsigned short* __restrict__ kb,
    const unsigned short* __restrict__ vtb, const int* __restrict__ pmask,
    unsigned short* __restrict__ ctxb)
{
  const int S = 4096, WIN = 256;
  const float NEG = -1e38f;
  __shared__ __align__(16) unsigned short Ks[2][64 * 64];     // 16 KB
  __shared__ __align__(16) unsigned short Vts[2][64 * 64];    // 16 KB
  __shared__ __align__(16) unsigned short Ps[4][2][16 * 64];  // 16 KB (per wave, per q-set)

  int bid0 = blockIdx.x;
  int bid = (bid0 & 7) * (gridDim.x >> 3) + (bid0 >> 3);   // XCD swizzle: 4 heads per XCD L2
  int qt = bid & 31;            // S/128 tiles
  int bh = bid >> 5;
  int b = bh >> 4, h = bh & 15;

  const unsigned short* Q  = qb + (size_t)bh * S * 64;
  const unsigned short* Kg = kb + (size_t)bh * S * 64;
  const unsigned short* Vt = vtb + (size_t)bh * 64 * S;
  const int* pmrow = pmask + (size_t)b * S;

  int tid = threadIdx.x;
  int lane = tid & 63, w = tid >> 6;    // 4 waves
  int l16 = lane & 15, g = lane >> 4;

  int q0 = qt * 128;
  int Q0 = q0 + w * 32;                 // this wave's 32 query rows (2 q-sets of 16)

  short8 qf[2][2];
  #pragma unroll
  for (int qs = 0; qs < 2; ++qs)
    #pragma unroll
    for (int hh = 0; hh < 2; ++hh)
      qf[qs][hh] = *(const short8*)&Q[(size_t)(Q0 + qs * 16 + l16) * 64 + hh * 32 + g * 8];

  f32x4 ctx[2][4];
  #pragma unroll
  for (int qs = 0; qs < 2; ++qs)
    #pragma unroll
    for (int dt = 0; dt < 4; ++dt) ctx[qs][dt] = (f32x4){0.f, 0.f, 0.f, 0.f};
  float lrun[2][4] = {{0.f,0.f,0.f,0.f},{0.f,0.f,0.f,0.f}};

  int kt0 = (q0 - WIN) >> 6; if (kt0 < 0) kt0 = 0;
  int kt1 = (q0 + 127 + WIN) >> 6; if (kt1 > 63) kt1 = 63;
  int nt = kt1 - kt0 + 1;

  // 256 threads stage one 64x64 K-unit and one 64x64 Vt-unit (8 KB each, 2 gloads ea.)
#define STAGE(BUF, KT) do {                                                       \
    int kb_ = (KT) * 64;                                                          \
    _Pragma("unroll")                                                             \
    for (int r_ = 0; r_ < 2; ++r_) {                                              \
      int idx_ = tid + 256 * r_;                                                  \
      int row_ = idx_ >> 3, s_ = idx_ & 7;                                        \
      int c_ = (s_ ^ (row_ & 7)) << 3;                                            \
      GLD_LDS16(Kg + (size_t)(kb_ + row_) * 64 + c_, &Ks[BUF][idx_ << 3]);        \
      GLD_LDS16(Vt + (size_t)row_ * S + kb_ + c_, &Vts[BUF][idx_ << 3]);          \
    }                                                                             \
  } while (0)

  STAGE(0, kt0);
  asm volatile("s_waitcnt vmcnt(0)" ::: "memory");
  __syncthreads();

  int cur = 0;
  for (int it = 0; it < nt; ++it) {
    int kbase = (kt0 + it) * 64;
    if (it + 1 < nt) STAGE(cur ^ 1, kt0 + it + 1);

    // union band-need for this wave's 32 rows (wave-uniform)
    bool need = (kbase >= Q0 - 319) && (kbase <= Q0 + 287);
    if (need) {
      unsigned long long bm = __ballot(pmrow[kbase + lane] != 0);
      bool allv = (~bm == 0ULL);
      // per-q-set "whole tile in band" fast path (out-of-band q-set -> exact zeros)
      bool full0 = (kbase >= Q0 - 241) && (kbase <= Q0 + 193);
      bool full1 = (kbase >= Q0 - 225) && (kbase <= Q0 + 209);   // X1 = Q0+16

      __builtin_amdgcn_s_setprio(1);
      #pragma unroll
      for (int k4 = 0; k4 < 4; ++k4) {
        int krow = k4 * 16 + l16;
        // shared K fragment pair (q-set independent) -- read ONCE
        short8 kf0 = *(const short8*)&Ks[cur][(krow << 6) + ((g ^ (l16 & 7)) << 3)];
        f32x4 s0 = __builtin_amdgcn_mfma_f32_16x16x32_bf16(qf[0][0], kf0,
                     (f32x4){0.f, 0.f, 0.f, 0.f}, 0, 0, 0);
        f32x4 s1 = __builtin_amdgcn_mfma_f32_16x16x32_bf16(qf[1][0], kf0,
                     (f32x4){0.f, 0.f, 0.f, 0.f}, 0, 0, 0);
        short8 kf1 = *(const short8*)&Ks[cur][(krow << 6) + (((4 + g) ^ (l16 & 7)) << 3)];
        s0 = __builtin_amdgcn_mfma_f32_16x16x32_bf16(qf[0][1], kf1, s0, 0, 0, 0);
        s1 = __builtin_amdgcn_mfma_f32_16x16x32_bf16(qf[1][1], kf1, s1, 0, 0, 0);

        // fused mask + exp2 + P-store for both q-sets (score regs die here)
        int col = k4 * 16 + l16;
        int kg = kbase + col;
        unsigned bit = (unsigned)(bm >> col) & 1u;
        #pragma unroll
        for (int jj = 0; jj < 4; ++jj) {
          int row = g * 4 + jj;
          int pofs = (row << 6) + ((((col >> 3) ^ (row & 7)) << 3) | (col & 7));
          {   // q-set 0
            float sv = s0[jj];
            if (!full0) {
              int dq = kg - (Q0 + row) + WIN;
              sv = ((unsigned)dq <= 2u * WIN) ? sv : NEG;
            }
            float p = exp2_fast(sv);
            if (!allv) p = bit ? p : 0.f;
            lrun[0][jj] += p;
            Ps[w][0][pofs] = f2bf_fast(p);
          }
          {   // q-set 1
            float sv = s1[jj];
            if (!full1) {
              int dq = kg - (Q0 + 16 + row) + WIN;
              sv = ((unsigned)dq <= 2u * WIN) ? sv : NEG;
            }
            float p = exp2_fast(sv);
            if (!allv) p = bit ? p : 0.f;
            lrun[1][jj] += p;
            Ps[w][1][pofs] = f2bf_fast(p);
          }
        }
      }
      __builtin_amdgcn_s_setprio(0);

      asm volatile("s_waitcnt lgkmcnt(0)" ::: "memory");  // P writes visible wave-wide
      __builtin_amdgcn_sched_barrier(0);

      // PV: P fragments per q-set; V fragment pairs read ONCE, feed both q-sets
      short8 pf00 = *(const short8*)&Ps[w][0][(l16 << 6) + ((g ^ (l16 & 7)) << 3)];
      short8 pf01 = *(const short8*)&Ps[w][0][(l16 << 6) + (((4 + g) ^ (l16 & 7)) << 3)];
      short8 pf10 = *(const short8*)&Ps[w][1][(l16 << 6) + ((g ^ (l16 & 7)) << 3)];
      short8 pf11 = *(const short8*)&Ps[w][1][(l16 << 6) + (((4 + g) ^ (l16 & 7)) << 3)];
      __builtin_amdgcn_s_setprio(1);
      #pragma unroll
      for (int dt = 0; dt < 4; ++dt) {
        int drow = dt * 16 + l16;
        short8 vf0 = *(const short8*)&Vts[cur][(drow << 6) + ((g ^ (drow & 7)) << 3)];
        ctx[0][dt] = __builtin_amdgcn_mfma_f32_16x16x32_bf16(pf00, vf0, ctx[0][dt], 0, 0, 0);
        ctx[1][dt] = __builtin_amdgcn_mfma_f32_16x16x32_bf16(pf10, vf0, ctx[1][dt], 0, 0, 0);
        short8 vf1 = *(const short8*)&Vts[cur][(drow << 6) + (((4 + g) ^ (drow & 7)) << 3)];
        ctx[0][dt] = __builtin_amdgcn_mfma_f32_16x16x32_bf16(pf01, vf1, ctx[0][dt], 0, 0, 0);
        ctx[1][dt] = __builtin_amdgcn_mfma_f32_16x16x32_bf16(pf11, vf1, ctx[1][dt], 0, 0, 0);
      }
      __builtin_amdgcn_s_setprio(0);
    }

    if (it + 1 < nt) {
      asm volatile("s_waitcnt vmcnt(0)" ::: "memory");  // next tile landed (issued pre-compute)
      __syncthreads();                                   // all waves done with cur
      cur ^= 1;
    }
  }
#undef STAGE

  // denominator reduce (once) + write ctx as bf16 in [B][S][H*64]
  #pragma unroll
  for (int qs = 0; qs < 2; ++qs) {
    #pragma unroll
    for (int jj = 0; jj < 4; ++jj) {
      float ps = lrun[qs][jj];
      #pragma unroll
      for (int mk = 1; mk < 16; mk <<= 1) ps += __shfl_xor(ps, mk);
      float rc = (ps > 0.f) ? (1.f / ps) : 0.f;
      int qrow = Q0 + qs * 16 + g * 4 + jj;
      size_t base = ((size_t)b * S + qrow) * 1024 + h * 64;
      #pragma unroll
      for (int dt = 0; dt < 4; ++dt)
        ctxb[base + dt * 16 + l16] = f2bf(ctx[qs][dt][jj] * rc);
    }
  }
}

// ---------------- launch ----------------------------------------------------------------
extern "C" void kernel_launch(void* const* d_in, const int* in_sizes, int n_in,
                              void* d_out, int out_size, void* d_ws, size_t ws_size,
                              hipStream_t stream) {
  const float* x     = (const float*)d_in[0];
  const int*   pmask = (const int*)d_in[1];
  const float* Wqkv  = (const float*)d_in[2];
  const float* bqkv  = (const float*)d_in[3];
  const float* Wo    = (const float*)d_in[4];
  const float* bo    = (const float*)d_in[5];

  // Memory map (56MB of ws + d_out doubling as q/k scratch):
  //   ws:    xb@0 (16MB) | Wqkvb@16MB (6MB) | Wob@22MB (2MB) | vtb@24MB (16MB) | ctxb@40MB (16MB)
  //   d_out: qbuf@0 (16MB) | kbuf@16MB (16MB)  -- dead before final GEMM overwrites d_out
  char* wsp = (char*)d_ws;
  unsigned short* xb    = (unsigned short*)(wsp);
  unsigned short* Wqkvb = (unsigned short*)(wsp + (size_t)(16u << 20));
  unsigned short* Wob   = (unsigned short*)(wsp + (size_t)(22u << 20));
  unsigned short* vtb   = (unsigned short*)(wsp + (size_t)(24u << 20));
  unsigned short* ctxb  = (unsigned short*)(wsp + (size_t)(40u << 20));
  unsigned short* qbuf  = (unsigned short*)d_out;
  unsigned short* kbuf  = (unsigned short*)d_out + (size_t)8388608;  // +16MB

  cvt_all_kernel<<<6144, 256, 0, stream>>>(x, Wqkv, Wo, xb, Wqkvb, Wob);

  gemm_bt<0><<<(8192 / 128) * (3072 / 128), 256, 0, stream>>>(
      xb, Wqkvb, bqkv, qbuf, kbuf, vtb, 8192, 3072, 1024, 3072 / 128);

  attn_kernel<<<1024, 256, 0, stream>>>(qbuf, kbuf, vtb, pmask, ctxb);

  gemm_bt<1><<<(8192 / 128) * (1024 / 128), 256, 0, stream>>>(
      ctxb, Wob, bo, d_out, nullptr, nullptr, 8192, 1024, 1024, 1024 / 128);
}

// Round 15
// 141.721 us; speedup vs baseline: 1.1092x; 1.0804x over previous
//
#include <hip/hip_runtime.h>
#include <hip/hip_bf16.h>
#include <stdint.h>

typedef __attribute__((ext_vector_type(8))) short short8;
typedef __attribute__((ext_vector_type(4))) float f32x4;

#define QSCALE 0.18033688011112042f   // (1/8) * log2(e): folds softmax /sqrt(64) AND exp->exp2

__device__ __forceinline__ unsigned short f2bf(float f) {
  unsigned int u = __builtin_bit_cast(unsigned int, f);
  u += 0x7FFFu + ((u >> 16) & 1u);   // RNE
  return (unsigned short)(u >> 16);
}

__device__ __forceinline__ unsigned short f2bf_fast(float f) {
  __hip_bfloat16 h = __float2bfloat16(f);     // compiler emits good cvt (m240)
  return __builtin_bit_cast(unsigned short, h);
}

__device__ __forceinline__ float exp2_fast(float x) {
  float r; asm("v_exp_f32 %0, %1" : "=v"(r) : "v"(x)); return r;   // 2^x
}

#define GLD_LDS16(gp, lp) \
  __builtin_amdgcn_global_load_lds((const __attribute__((address_space(1))) void*)(gp), \
                                   (__attribute__((address_space(3))) void*)(lp), 16, 0, 0)

// ---------------- fused fp32 -> bf16 convert for x / Wqkv (q-rows pre-scaled) / Wo ------
__global__ __launch_bounds__(256) void cvt_all_kernel(
    const float* __restrict__ x, const float* __restrict__ Wqkv, const float* __restrict__ Wo,
    unsigned short* __restrict__ xb, unsigned short* __restrict__ Wqkvb,
    unsigned short* __restrict__ Wob) {
  int i = blockIdx.x * 256 + threadIdx.x;          // indexes 8-float chunks
  const float* src; unsigned short* dst; int local; float scale = 1.0f;
  if (i < 1048576) { src = x; dst = xb; local = i; }
  else if (i < 1048576 + 393216) {
    local = i - 1048576; src = Wqkv; dst = Wqkvb;
    int row = (local * 8) >> 10;                   // K = 1024 per row
    if (((row >> 6) % 3) == 0) scale = QSCALE;     // q rows: fold 1/sqrt(64) * log2(e)
  } else { local = i - 1441792; src = Wo; dst = Wob; }
  const float4* s4 = (const float4*)src;
  float4 a = s4[local * 2], b = s4[local * 2 + 1];
  uint4 o;
  o.x = (unsigned)f2bf(a.x * scale) | ((unsigned)f2bf(a.y * scale) << 16);
  o.y = (unsigned)f2bf(a.z * scale) | ((unsigned)f2bf(a.w * scale) << 16);
  o.z = (unsigned)f2bf(b.x * scale) | ((unsigned)f2bf(b.y * scale) << 16);
  o.w = (unsigned)f2bf(b.z * scale) | ((unsigned)f2bf(b.w * scale) << 16);
  *(uint4*)(dst + (size_t)local * 8) = o;
}

// ---------------- 128x128-tile bf16 GEMM, C = A @ B^T (+bias), m97 structure ----------
// EPI 0: scatter q/k as [B][H][S][64], v TRANSPOSED as [B][H][64][S]   EPI 1: fp32 [M][N]
template<int EPI>
__global__ __launch_bounds__(256, 4) void gemm_bt(
    const unsigned short* __restrict__ A, const unsigned short* __restrict__ Bw,
    const float* __restrict__ bias, void* o0, void* o1, void* o2,
    int M, int N, int K, int nbc)
{
  __shared__ __align__(16) unsigned short Asm[128 * 64];
  __shared__ __align__(16) unsigned short Bsm[128 * 64];
  int bid = blockIdx.x;
  int bc = bid % nbc, br = bid / nbc;
  int tid = threadIdx.x;
  int lane = tid & 63, w = tid >> 6;
  int l16 = lane & 15, g = lane >> 4;
  int wr = w >> 1, wc = w & 1;
  f32x4 acc[4][4];
  #pragma unroll
  for (int i = 0; i < 4; i++)
    #pragma unroll
    for (int j = 0; j < 4; j++) acc[i][j] = (f32x4){0.f, 0.f, 0.f, 0.f};

  const int nkt = K >> 6;
  for (int kt = 0; kt < nkt; ++kt) {
    __syncthreads();
    #pragma unroll
    for (int r = 0; r < 4; ++r) {
      int idx = tid + 256 * r;            // lane-contiguous per wave (gload_lds linear dest)
      int row = idx >> 3, s = idx & 7;
      int gofs = ((s ^ (row & 7)) << 3) + (kt << 6);   // pre-swizzled global source
      GLD_LDS16(A + (size_t)(br * 128 + row) * K + gofs, &Asm[idx << 3]);
      GLD_LDS16(Bw + (size_t)(bc * 128 + row) * K + gofs, &Bsm[idx << 3]);
    }
    __syncthreads();
    #pragma unroll
    for (int kk = 0; kk < 2; ++kk) {
      short8 af[4], bf[4];
      #pragma unroll
      for (int i = 0; i < 4; i++) {
        int rowa = wr * 64 + i * 16 + l16;
        af[i] = *(const short8*)&Asm[(rowa << 6) + ((((kk << 2) + g) ^ (rowa & 7)) << 3)];
        int rowb = wc * 64 + i * 16 + l16;
        bf[i] = *(const short8*)&Bsm[(rowb << 6) + ((((kk << 2) + g) ^ (rowb & 7)) << 3)];
      }
      #pragma unroll
      for (int i = 0; i < 4; i++)
        #pragma unroll
        for (int j = 0; j < 4; j++)
          acc[i][j] = __builtin_amdgcn_mfma_f32_16x16x32_bf16(af[i], bf[j], acc[i][j], 0, 0, 0);
    }
  }
  // epilogue: D row = g*4+jj, col = l16 (m89-verified layout)
  #pragma unroll
  for (int i = 0; i < 4; i++) {
    #pragma unroll
    for (int j = 0; j < 4; j++) {
      int n = bc * 128 + wc * 64 + j * 16 + l16;
      int m0 = br * 128 + wr * 64 + i * 16 + g * 4;
      if (EPI == 0) {
        int t = (n >> 6) % 3;
        int hh = n / 192, e = n & 63;
        float bval = bias[n]; if (t == 0) bval *= QSCALE;
        int bb = m0 >> 12, s0 = m0 & 4095;          // S = 4096; m0 4-aligned, no b-straddle
        if (t == 2) {                               // v: transposed [bh][e][S], b64-packed
          unsigned short p0 = f2bf(acc[i][j][0] + bval);
          unsigned short p1 = f2bf(acc[i][j][1] + bval);
          unsigned short p2 = f2bf(acc[i][j][2] + bval);
          unsigned short p3 = f2bf(acc[i][j][3] + bval);
          uint2 pk;
          pk.x = (unsigned)p0 | ((unsigned)p1 << 16);
          pk.y = (unsigned)p2 | ((unsigned)p3 << 16);
          unsigned short* vt = (unsigned short*)o2;
          *(uint2*)&vt[(((size_t)(bb * 16 + hh) * 64 + e) << 12) + s0] = pk;
        } else {
          unsigned short* dst = (unsigned short*)(t == 0 ? o0 : o1);
          #pragma unroll
          for (int jj = 0; jj < 4; jj++)
            dst[((((size_t)(bb * 16 + hh) << 12) + s0 + jj) << 6) + e] = f2bf(acc[i][j][jj] + bval);
        }
      } else {
        float* o = (float*)o0;
        float bval = bias[n];
        #pragma unroll
        for (int jj = 0; jj < 4; jj++)
          o[(size_t)(m0 + jj) * N + n] = acc[i][j][jj] + bval;
      }
    }
  }
}

// ---------------- banded flash attention (QBLK=128, ONE q-set per wave) ----------------
// r12-exact: proven best (141.7us total, attn ~42us, conflicts=0, no spill).
// grid: (S/128) * B*H = 1024 blocks; 8 waves/block (512 thr), wave owns 16 query rows.
// LDS 48KB -> 3 blocks/CU -> 24 waves/CU. r13 (32x32 frags: structural 4-way bank
// conflict) and r14 (frag-sharing at 4 waves: TLP halved) both regressed -- this
// template's TLP/conflict balance is the measured optimum.
__global__ __launch_bounds__(512, 4) void attn_kernel(
    const unsigned short* __restrict__ qb, const unsigned short* __restrict__ kb,
    const unsigned short* __restrict__ vtb, const int* __restrict__ pmask,
    unsigned short* __restrict__ ctxb)
{
  const int S = 4096, HD = 64, WIN = 256;
  const float NEG = -1e38f;
  __shared__ __align__(16) unsigned short Ks[2][64 * 64];    // 16 KB
  __shared__ __align__(16) unsigned short Vts[2][64 * 64];   // 16 KB
  __shared__ __align__(16) unsigned short Ps[8][16 * 64];    // 16 KB (per wave)

  int bid0 = blockIdx.x;
  int bid = (bid0 & 7) * (gridDim.x >> 3) + (bid0 >> 3);   // XCD swizzle: 4 heads per XCD L2
  int qt = bid & 31;            // S/128 tiles
  int bh = bid >> 5;
  int b = bh >> 4, h = bh & 15;

  const unsigned short* Q  = qb + (size_t)bh * S * HD;
  const unsigned short* Kg = kb + (size_t)bh * S * HD;
  const unsigned short* Vt = vtb + (size_t)bh * HD * S;
  const int* pmrow = pmask + (size_t)b * S;

  int tid = threadIdx.x;
  int lane = tid & 63, w = tid >> 6;
  int l16 = lane & 15, g = lane >> 4;

  int q0 = qt * 128;
  int Q0 = q0 + w * 16;         // this wave's 16 query rows

  short8 qf[2];
  #pragma unroll
  for (int hh = 0; hh < 2; ++hh)
    qf[hh] = *(const short8*)&Q[(size_t)(Q0 + l16) * HD + hh * 32 + g * 8];

  f32x4 ctx[4];
  #pragma unroll
  for (int dt = 0; dt < 4; ++dt) ctx[dt] = (f32x4){0.f, 0.f, 0.f, 0.f};
  float lrun[4] = {0.f, 0.f, 0.f, 0.f};

  int kt0 = (q0 - WIN) >> 6; if (kt0 < 0) kt0 = 0;
  int kt1 = (q0 + 127 + WIN) >> 6; if (kt1 > 63) kt1 = 63;
  int nt = kt1 - kt0 + 1;

  // 512 threads stage one 64x64 K-unit and one 64x64 Vt-unit (8 KB each, 1 gload ea.)
#define STAGE(BUF, KT) do {                                                       \
    int kb_ = (KT) * 64;                                                          \
    int row_ = tid >> 3, s_ = tid & 7;                                            \
    int c_ = (s_ ^ (row_ & 7)) << 3;                                              \
    GLD_LDS16(Kg + (size_t)(kb_ + row_) * HD + c_, &Ks[BUF][tid << 3]);           \
    GLD_LDS16(Vt + (size_t)row_ * S + kb_ + c_, &Vts[BUF][tid << 3]);             \
  } while (0)

  STAGE(0, kt0);
  asm volatile("s_waitcnt vmcnt(0)" ::: "memory");
  __syncthreads();

  int cur = 0;
  for (int it = 0; it < nt; ++it) {
    int kbase = (kt0 + it) * 64;
    if (it + 1 < nt) STAGE(cur ^ 1, kt0 + it + 1);

    // wave-uniform: does this wave's 16-row band touch this tile?
    bool need = (kbase >= Q0 - 319) && (kbase <= Q0 + 271);

    if (need) {
      // tile padding mask: one ballot; all-valid fast path (bench mask is all-ones)
      unsigned long long bm = __ballot(pmrow[kbase + lane] != 0);
      bool allv = (~bm == 0ULL);
      bool full = (kbase >= Q0 - 241) && (kbase <= Q0 + 193);   // whole tile in band

      // QK^T : S[q = g*4+jj][key = 16*k4 + l16]  (q pre-scaled by log2e/8)
      f32x4 sc[4];
      __builtin_amdgcn_s_setprio(1);
      #pragma unroll
      for (int k4 = 0; k4 < 4; ++k4) {
        int krow = k4 * 16 + l16;
        f32x4 s = (f32x4){0.f, 0.f, 0.f, 0.f};
        short8 kf0 = *(const short8*)&Ks[cur][(krow << 6) + ((g ^ (l16 & 7)) << 3)];
        s = __builtin_amdgcn_mfma_f32_16x16x32_bf16(qf[0], kf0, s, 0, 0, 0);
        short8 kf1 = *(const short8*)&Ks[cur][(krow << 6) + (((4 + g) ^ (l16 & 7)) << 3)];
        s = __builtin_amdgcn_mfma_f32_16x16x32_bf16(qf[1], kf1, s, 0, 0, 0);
        sc[k4] = s;
      }
      __builtin_amdgcn_s_setprio(0);

      int qbase = Q0 + g * 4;
      if (!full) {                      // band-edge tiles only: mask out-of-band
        #pragma unroll
        for (int k4 = 0; k4 < 4; ++k4) {
          int kg = kbase + k4 * 16 + l16;
          #pragma unroll
          for (int jj = 0; jj < 4; ++jj) {
            int dq = kg - (qbase + jj) + WIN;      // in [0,2*WIN] iff in band
            sc[k4][jj] = ((unsigned)dq <= 2u * WIN) ? sc[k4][jj] : NEG;
          }
        }
      }
      // exp2 + store P (scores already in log2 domain); padding via ballot bit
      #pragma unroll
      for (int k4 = 0; k4 < 4; ++k4) {
        int col = k4 * 16 + l16;
        unsigned bit = (unsigned)(bm >> col) & 1u;   // key valid?
        #pragma unroll
        for (int jj = 0; jj < 4; ++jj) {
          float p = exp2_fast(sc[k4][jj]);
          if (!allv) p = bit ? p : 0.f;
          lrun[jj] += p;
          int row = g * 4 + jj;        // Ps XOR-swizzle: blk = (col>>3)^(row&7)
          Ps[w][(row << 6) + ((((col >> 3) ^ (row & 7)) << 3) | (col & 7))] = f2bf_fast(p);
        }
      }

      asm volatile("s_waitcnt lgkmcnt(0)" ::: "memory");  // P writes visible wave-wide
      __builtin_amdgcn_sched_barrier(0);
      // PV : ctx[q][d] += P[16q x 64keys] @ Vt[64d x 64keys]
      short8 pf0 = *(const short8*)&Ps[w][(l16 << 6) + ((g ^ (l16 & 7)) << 3)];
      short8 pf1 = *(const short8*)&Ps[w][(l16 << 6) + (((4 + g) ^ (l16 & 7)) << 3)];
      __builtin_amdgcn_s_setprio(1);
      #pragma unroll
      for (int dt = 0; dt < 4; ++dt) {
        int drow = dt * 16 + l16;
        short8 vf0 = *(const short8*)&Vts[cur][(drow << 6) + ((g ^ (drow & 7)) << 3)];
        ctx[dt] = __builtin_amdgcn_mfma_f32_16x16x32_bf16(pf0, vf0, ctx[dt], 0, 0, 0);
        short8 vf1 = *(const short8*)&Vts[cur][(drow << 6) + (((4 + g) ^ (drow & 7)) << 3)];
        ctx[dt] = __builtin_amdgcn_mfma_f32_16x16x32_bf16(pf1, vf1, ctx[dt], 0, 0, 0);
      }
      __builtin_amdgcn_s_setprio(0);
    }

    if (it + 1 < nt) {
      asm volatile("s_waitcnt vmcnt(0)" ::: "memory");  // next tile landed (issued pre-compute)
      __syncthreads();                                   // all waves done with cur
      cur ^= 1;
    }
  }
#undef STAGE

  // denominator reduce (once) + write ctx as bf16 in [B][S][H*64]
  #pragma unroll
  for (int jj = 0; jj < 4; ++jj) {
    float ps = lrun[jj];
    #pragma unroll
    for (int mk = 1; mk < 16; mk <<= 1) ps += __shfl_xor(ps, mk);
    float rc = (ps > 0.f) ? (1.f / ps) : 0.f;
    int qrow = Q0 + g * 4 + jj;
    size_t base = ((size_t)b * S + qrow) * 1024 + h * 64;
    #pragma unroll
    for (int dt = 0; dt < 4; ++dt)
      ctxb[base + dt * 16 + l16] = f2bf(ctx[dt][jj] * rc);
  }
}

// ---------------- launch ----------------------------------------------------------------
extern "C" void kernel_launch(void* const* d_in, const int* in_sizes, int n_in,
                              void* d_out, int out_size, void* d_ws, size_t ws_size,
                              hipStream_t stream) {
  const float* x     = (const float*)d_in[0];
  const int*   pmask = (const int*)d_in[1];
  const float* Wqkv  = (const float*)d_in[2];
  const float* bqkv  = (const float*)d_in[3];
  const float* Wo    = (const float*)d_in[4];
  const float* bo    = (const float*)d_in[5];

  // Memory map (56MB of ws + d_out doubling as q/k scratch):
  //   ws:    xb@0 (16MB) | Wqkvb@16MB (6MB) | Wob@22MB (2MB) | vtb@24MB (16MB) | ctxb@40MB (16MB)
  //   d_out: qbuf@0 (16MB) | kbuf@16MB (16MB)  -- dead before final GEMM overwrites d_out
  char* wsp = (char*)d_ws;
  unsigned short* xb    = (unsigned short*)(wsp);
  unsigned short* Wqkvb = (unsigned short*)(wsp + (size_t)(16u << 20));
  unsigned short* Wob   = (unsigned short*)(wsp + (size_t)(22u << 20));
  unsigned short* vtb   = (unsigned short*)(wsp + (size_t)(24u << 20));
  unsigned short* ctxb  = (unsigned short*)(wsp + (size_t)(40u << 20));
  unsigned short* qbuf  = (unsigned short*)d_out;
  unsigned short* kbuf  = (unsigned short*)d_out + (size_t)8388608;  // +16MB

  cvt_all_kernel<<<6144, 256, 0, stream>>>(x, Wqkv, Wo, xb, Wqkvb, Wob);

  gemm_bt<0><<<(8192 / 128) * (3072 / 128), 256, 0, stream>>>(
      xb, Wqkvb, bqkv, qbuf, kbuf, vtb, 8192, 3072, 1024, 3072 / 128);

  attn_kernel<<<1024, 512, 0, stream>>>(qbuf, kbuf, vtb, pmask, ctxb);

  gemm_bt<1><<<(8192 / 128) * (1024 / 128), 256, 0, stream>>>(
      ctxb, Wob, bo, d_out, nullptr, nullptr, 8192, 1024, 1024, 1024 / 128);
}